// Round 1
// baseline (721.675 us; speedup 1.0000x reference)
//
#include <hip/hip_runtime.h>
#include <hip/hip_bf16.h>

#define NN 4096
#define FF 32
#define EE 65536
#define GG 13

typedef float floatx4 __attribute__((ext_vector_type(4)));
typedef __bf16 bf16x8 __attribute__((ext_vector_type(8)));
typedef short short8 __attribute__((ext_vector_type(8)));

__device__ inline unsigned short f2bf(float f) {
    unsigned u = __float_as_uint(f);
    u += 0x7FFFu + ((u >> 16) & 1u);          // RNE to bf16
    return (unsigned short)(u >> 16);
}

// ---------------- B-fragment prep kernels ----------------
// Bfrag layout: element (ks, t, c, kl) at ((ks*NT + t)*512 + c*32 + kl), bf16.
// ks = k/32 (K-step), t = col/16 (n-tile), c = col&15, kl = k&31.
// Lane l of the MFMA wave reads 8 contiguous bf16 at c=l&15, kl=(l>>4)*8 -> dwordx4.

__global__ void k_prep1(const float* __restrict__ x, unsigned short* __restrict__ B) {
    int tid = blockIdx.x * 256 + threadIdx.x;           // < 4096*32
    int k = tid >> 5, col = tid & 31;
    float v = fabsf(x[tid]);
    B[(((k >> 5) * 2 + (col >> 4)) << 9) + ((col & 15) << 5) + (k & 31)] = f2bf(v);
}

__global__ void k_prep2(const float* __restrict__ P1, unsigned short* __restrict__ B) {
    int tid = blockIdx.x * 256 + threadIdx.x;           // < 4096*96
    int k = tid / 96, jf = tid % 96;
    int j = jf >> 5, f = jf & 31;
    float v = fabsf(P1[((1 + j) * NN + k) * FF + f]);   // |y1[j][k][f]|
    B[(((k >> 5) * 6 + (jf >> 4)) << 9) + ((jf & 15) << 5) + (k & 31)] = f2bf(v);
}

__global__ void k_prep3(const float* __restrict__ P2, unsigned short* __restrict__ B) {
    int tid = blockIdx.x * 256 + threadIdx.x;           // < 4096*288
    int k = tid / 288, cc = tid % 288;
    int k3 = cc / 96, jf = cc % 96;
    float v = fabsf(P2[((1 + k3) * NN + k) * 96 + jf]); // |y2[j][k3][k][f]|, col = k3*96+j*32+f
    B[(((k >> 5) * 18 + (cc >> 4)) << 9) + ((cc & 15) << 5) + (k & 31)] = f2bf(v);
}

// ---------------- Main streaming matmul ----------------
// Block = 512 thr (8 waves). Block owns (mat, 16 rows, all NT*16 cols); waves split K
// into 8x512 chunks; fp32 A loaded direct-to-reg (dwordx4 x2 / K-step), cvt to bf16,
// B frags from pre-packed L2-resident buffer. No barriers in K-loop. LDS reduce at end.
template <int NT>
__global__ __launch_bounds__(512) void k_pass(const float* __restrict__ Umat,
                                              const float* __restrict__ Psi,
                                              const unsigned short* __restrict__ Bfrag,
                                              float* __restrict__ Pout) {
    constexpr int NC = NT * 16;
    int tile = blockIdx.x;
    int mat = blockIdx.y;
    const float* A = (mat == 0) ? Umat : (Psi + (size_t)(mat - 1) * NN * NN);
    int tid = threadIdx.x;
    int wave = tid >> 6, lane = tid & 63;
    int c15 = lane & 15, q = lane >> 4;
    int row = tile * 16 + c15;
    const float* arow = A + (size_t)row * NN + wave * 512 + q * 8;
    const unsigned short* bbase = Bfrag + (size_t)(wave * 16) * NT * 512 + (c15 << 5) + (q << 3);

    floatx4 acc[NT];
#pragma unroll
    for (int t = 0; t < NT; t++) acc[t] = (floatx4){0.f, 0.f, 0.f, 0.f};

    for (int s = 0; s < 16; s++) {
        const float* ap = arow + s * 32;
        floatx4 a0 = *(const floatx4*)ap;
        floatx4 a1 = *(const floatx4*)(ap + 4);
        short8 av;
        av[0] = f2bf(a0[0]); av[1] = f2bf(a0[1]); av[2] = f2bf(a0[2]); av[3] = f2bf(a0[3]);
        av[4] = f2bf(a1[0]); av[5] = f2bf(a1[1]); av[6] = f2bf(a1[2]); av[7] = f2bf(a1[3]);
        bf16x8 ab = __builtin_bit_cast(bf16x8, av);
        const unsigned short* bp = bbase + (size_t)s * NT * 512;
#pragma unroll
        for (int t = 0; t < NT; t++) {
            short8 bv = *(const short8*)(bp + t * 512);
            acc[t] = __builtin_amdgcn_mfma_f32_16x16x32_bf16(
                ab, __builtin_bit_cast(bf16x8, bv), acc[t], 0, 0, 0);
        }
    }

    // reduce partial K-sums across the 8 waves (C/D layout: col=lane&15, row=q*4+r)
    __shared__ float cs[16 * NC];
    for (int w = 0; w < 8; w++) {
        if (wave == w) {
#pragma unroll
            for (int t = 0; t < NT; t++)
#pragma unroll
                for (int r = 0; r < 4; r++) {
                    int idx = (q * 4 + r) * NC + t * 16 + c15;
                    if (w == 0) cs[idx] = acc[t][r]; else cs[idx] += acc[t][r];
                }
        }
        __syncthreads();
    }
    float* orow = Pout + ((size_t)mat * NN + (size_t)tile * 16) * NC;
    for (int i = tid; i < 16 * NC; i += 512) orow[i] = cs[i];
}

// ---------------- GAT stage ----------------
// h[g][n][hc] = sum_f coef[g][n][f] * gatW[g][f][hc]; coefs read in place from P1/P2/P3.
__global__ void k_h(const float* __restrict__ P1, const float* __restrict__ P2,
                    const float* __restrict__ P3, const float* __restrict__ gatW,
                    float* __restrict__ h) {
    int tid = blockIdx.x * 256 + threadIdx.x;  // exactly 13*4096*64
    int g = tid >> 18;
    int n = (tid & ((1 << 18) - 1)) >> 6;
    int hc = tid & 63;
    const float* crow;
    if (g == 0) crow = P1 + (size_t)n * FF;
    else if (g <= 3) crow = P2 + (size_t)n * 96 + (g - 1) * 32;
    else {
        int j = (g - 4) / 3, k3 = (g - 4) % 3;
        crow = P3 + (size_t)n * 288 + k3 * 96 + j * 32;
    }
    const float* wcol = gatW + g * (32 * 64) + hc;
    float a = 0.f;
#pragma unroll
    for (int f = 0; f < 32; f++) a += crow[f] * wcol[f * 64];
    h[tid] = a;
}

__global__ void k_esed(const float* __restrict__ h, const float* __restrict__ attS,
                       const float* __restrict__ attD, float* __restrict__ es,
                       float* __restrict__ ed) {
    int tid = blockIdx.x * 256 + threadIdx.x;  // exactly 13*4096
    int g = tid >> 12;
    const float* hrow = h + (size_t)tid * 64;
    const float* as = attS + g * 64;
    const float* ad = attD + g * 64;
    float e0 = 0, e1 = 0, d0 = 0, d1 = 0;
#pragma unroll
    for (int i = 0; i < 32; i++) {
        float v0 = hrow[i], v1 = hrow[32 + i];
        e0 += v0 * as[i];      e1 += v1 * as[32 + i];
        d0 += v0 * ad[i];      d1 += v1 * ad[32 + i];
    }
    es[tid * 2] = e0; es[tid * 2 + 1] = e1;
    ed[tid * 2] = d0; ed[tid * 2 + 1] = d1;
}

// CSR build over dst (self-loops appended as nodes)
__global__ void k_hist(const int* __restrict__ ei, int* __restrict__ cnt) {
    int e = blockIdx.x * 256 + threadIdx.x;  // exactly EE+NN
    int d = (e < EE) ? ei[EE + e] : (e - EE);
    atomicAdd(&cnt[d], 1);
}

__global__ void k_scan(const int* __restrict__ cnt, int* __restrict__ offs,
                       int* __restrict__ cursor) {
    int lane = threadIdx.x;  // 64 threads, 1 block
    int base = lane * 64;
    int s = 0;
    for (int i = 0; i < 64; i++) s += cnt[base + i];
    int x = s;
    for (int d = 1; d < 64; d <<= 1) {
        int y = __shfl_up(x, d);
        if (lane >= d) x += y;
    }
    int run = x - s;  // exclusive prefix of per-lane totals
    for (int i = 0; i < 64; i++) {
        offs[base + i] = run;
        cursor[base + i] = run;
        run += cnt[base + i];
    }
}

__global__ void k_scatter(const int* __restrict__ ei, int* __restrict__ cursor,
                          int* __restrict__ csr) {
    int e = blockIdx.x * 256 + threadIdx.x;  // exactly EE+NN
    int s, d;
    if (e < EE) { s = ei[e]; d = ei[EE + e]; } else { s = d = e - EE; }
    int pos = atomicAdd(&cursor[d], 1);
    csr[pos] = s;
}

// One wave per (branch g, dst node n); lane = head*32 + feat. Online softmax over edges.
__global__ void k_gat(const float* __restrict__ h, const float* __restrict__ es,
                      const float* __restrict__ ed, const int* __restrict__ offs,
                      const int* __restrict__ cnt, const int* __restrict__ csr,
                      const float* __restrict__ gatb, float* __restrict__ gact) {
    int w = (blockIdx.x * 256 + threadIdx.x) >> 6;  // exactly 13*4096 waves
    int lane = threadIdx.x & 63, hh = lane >> 5;
    int g = w >> 12, n = w & 4095;
    float myed = ed[w * 2 + hh];
    int start = offs[n], deg = cnt[n];
    const float* hg = h + (size_t)g * NN * 64;
    const float* esg = es + (size_t)g * NN * 2;
    float m = -INFINITY, z = 0.f, acc = 0.f;
    for (int i = 0; i < deg; i++) {
        int s = csr[start + i];
        float lg = esg[s * 2 + hh] + myed;
        lg = (lg > 0.f) ? lg : 0.2f * lg;               // leaky_relu(0.2)
        float nm = fmaxf(m, lg);
        float sc = __expf(m - nm);
        float we = __expf(lg - nm);
        z = z * sc + we;
        acc = acc * sc + we * hg[(size_t)s * 64 + lane];
        m = nm;
    }
    float o = acc / (z + 1e-16f) + gatb[g * 64 + lane];
    o = (o > 0.f) ? o : (__expf(o) - 1.f);              // elu
    gact[(size_t)w * 64 + lane] = o;
}

// Branch MLP: feat[n][g*64+k] = elu( gact[g][n][:] . mlpW[g][:,k] + mlpb[g][k] )
__global__ void k_mlp(const float* __restrict__ gact, const float* __restrict__ mlpW,
                      const float* __restrict__ mlpb, float* __restrict__ feat) {
    int tid = blockIdx.x * 256 + threadIdx.x;  // exactly 13*4096*64
    int g = tid >> 18;
    int n = (tid & ((1 << 18) - 1)) >> 6;
    int k = tid & 63;
    const float* grow = gact + ((size_t)g * NN + n) * 64;
    const float* wc = mlpW + (size_t)g * 64 * 64 + k;
    float a = mlpb[g * 64 + k];
#pragma unroll 8
    for (int i = 0; i < 64; i++) a += grow[i] * wc[i * 64];
    a = (a > 0.f) ? a : (__expf(a) - 1.f);              // elu (pre-head)
    feat[(size_t)n * 832 + g * 64 + k] = a;
}

// Head: logits = feat @ outW + outb, then log_softmax. One wave per node.
__global__ void k_final(const float* __restrict__ feat, const float* __restrict__ oW,
                        const float* __restrict__ ob, float* __restrict__ out) {
    int w = (blockIdx.x * 256 + threadIdx.x) >> 6;  // exactly 4096 waves
    int lane = threadIdx.x & 63;
    float a[10];
#pragma unroll
    for (int c = 0; c < 10; c++) a[c] = 0.f;
    const float* frow = feat + (size_t)w * 832;
#pragma unroll
    for (int i = 0; i < 13; i++) {
        float v = frow[i * 64 + lane];
        const float* wp = oW + (i * 64 + lane) * 10;
#pragma unroll
        for (int c = 0; c < 10; c++) a[c] += v * wp[c];
    }
#pragma unroll
    for (int off = 32; off >= 1; off >>= 1)
#pragma unroll
        for (int c = 0; c < 10; c++) a[c] += __shfl_down(a[c], off);
    if (lane == 0) {
        float m = -INFINITY;
#pragma unroll
        for (int c = 0; c < 10; c++) { a[c] += ob[c]; m = fmaxf(m, a[c]); }
        float s = 0.f;
#pragma unroll
        for (int c = 0; c < 10; c++) s += __expf(a[c] - m);
        float lse = m + __logf(s);
#pragma unroll
        for (int c = 0; c < 10; c++) out[w * 10 + c] = a[c] - lse;
    }
}

extern "C" void kernel_launch(void* const* d_in, const int* in_sizes, int n_in,
                              void* d_out, int out_size, void* d_ws, size_t ws_size,
                              hipStream_t stream) {
    const float* x    = (const float*)d_in[0];
    const int*   ei   = (const int*)d_in[1];
    const float* U    = (const float*)d_in[2];
    const float* psi  = (const float*)d_in[3];
    const float* gatW = (const float*)d_in[4];
    const float* attS = (const float*)d_in[5];
    const float* attD = (const float*)d_in[6];
    const float* gatb = (const float*)d_in[7];
    const float* mlpW = (const float*)d_in[8];
    const float* mlpb = (const float*)d_in[9];
    const float* oW   = (const float*)d_in[10];
    const float* ob   = (const float*)d_in[11];
    float* out = (float*)d_out;

    char* ws = (char*)d_ws;
    size_t off = 0;
    auto alloc = [&](size_t bytes) { char* p = ws + off; off += (bytes + 255) & ~(size_t)255; return p; };
    unsigned short* bf1 = (unsigned short*)alloc((size_t)NN * 32 * 2);
    float* P1           = (float*)alloc((size_t)4 * NN * 32 * 4);
    unsigned short* bf2 = (unsigned short*)alloc((size_t)NN * 96 * 2);
    float* P2           = (float*)alloc((size_t)4 * NN * 96 * 4);
    unsigned short* bf3 = (unsigned short*)alloc((size_t)NN * 288 * 2);
    float* P3           = (float*)alloc((size_t)NN * 288 * 4);
    float* h            = (float*)alloc((size_t)GG * NN * 64 * 4);
    float* es           = (float*)alloc((size_t)GG * NN * 2 * 4);
    float* ed           = (float*)alloc((size_t)GG * NN * 2 * 4);
    int* cnt            = (int*)alloc((size_t)NN * 4);
    int* offs           = (int*)alloc((size_t)NN * 4);
    int* cursor         = (int*)alloc((size_t)NN * 4);
    int* csr            = (int*)alloc((size_t)(EE + NN) * 4);
    float* gact         = (float*)alloc((size_t)GG * NN * 64 * 4);
    float* feat         = (float*)alloc((size_t)NN * 832 * 4);
    (void)ws_size; (void)in_sizes; (void)n_in; (void)out_size;

    // CSR build (independent of scattering passes)
    hipMemsetAsync(cnt, 0, NN * 4, stream);
    k_hist<<<(EE + NN) / 256, 256, 0, stream>>>(ei, cnt);
    k_scan<<<1, 64, 0, stream>>>(cnt, offs, cursor);
    k_scatter<<<(EE + NN) / 256, 256, 0, stream>>>(ei, cursor, csr);

    // Scattering passes
    k_prep1<<<(NN * 32) / 256, 256, 0, stream>>>(x, bf1);
    k_pass<2><<<dim3(NN / 16, 4), 512, 0, stream>>>(U, psi, bf1, P1);
    k_prep2<<<(NN * 96) / 256, 256, 0, stream>>>(P1, bf2);
    k_pass<6><<<dim3(NN / 16, 4), 512, 0, stream>>>(U, psi, bf2, P2);
    k_prep3<<<(NN * 288) / 256, 256, 0, stream>>>(P2, bf3);
    k_pass<18><<<dim3(NN / 16, 1), 512, 0, stream>>>(U, psi, bf3, P3);

    // GAT stage
    k_h<<<(GG * NN * 64) / 256, 256, 0, stream>>>(P1, P2, P3, gatW, h);
    k_esed<<<(GG * NN) / 256, 256, 0, stream>>>(h, attS, attD, es, ed);
    k_gat<<<(GG * NN * 64) / 256, 256, 0, stream>>>(h, es, ed, offs, cnt, csr, gatb, gact);
    k_mlp<<<(GG * NN * 64) / 256, 256, 0, stream>>>(gact, mlpW, mlpb, feat);
    k_final<<<(NN * 64) / 256, 256, 0, stream>>>(feat, oW, ob, out);
}

// Round 2
// 670.182 us; speedup vs baseline: 1.0768x; 1.0768x over previous
//
#include <hip/hip_runtime.h>
#include <hip/hip_bf16.h>

#define NN 4096
#define FF 32
#define EE 65536
#define GG 13

typedef float floatx4 __attribute__((ext_vector_type(4)));
typedef __bf16 bf16x8 __attribute__((ext_vector_type(8)));
typedef short short8 __attribute__((ext_vector_type(8)));

__device__ inline unsigned short f2bf(float f) {
    unsigned u = __float_as_uint(f);
    u += 0x7FFFu + ((u >> 16) & 1u);          // RNE to bf16
    return (unsigned short)(u >> 16);
}

// ---------------- B-fragment prep kernels ----------------
// Bfrag layout: element (ks, t, c, kl) at ((ks*NT + t)*512 + c*32 + kl), bf16.
// ks = k/32 (K-step), t = col/16 (n-tile), c = col&15, kl = k&31.
// Lane l of the MFMA wave reads 8 contiguous bf16 at c=l&15, kl=(l>>4)*8 -> dwordx4.

__global__ void k_prep1(const float* __restrict__ x, unsigned short* __restrict__ B) {
    int tid = blockIdx.x * 256 + threadIdx.x;           // < 4096*32
    int k = tid >> 5, col = tid & 31;
    float v = fabsf(x[tid]);
    B[(((k >> 5) * 2 + (col >> 4)) << 9) + ((col & 15) << 5) + (k & 31)] = f2bf(v);
}

__global__ void k_prep2(const float* __restrict__ P1, unsigned short* __restrict__ B) {
    int tid = blockIdx.x * 256 + threadIdx.x;           // < 4096*96
    int k = tid / 96, jf = tid % 96;
    int j = jf >> 5, f = jf & 31;
    float v = fabsf(P1[((1 + j) * NN + k) * FF + f]);   // |y1[j][k][f]|
    B[(((k >> 5) * 6 + (jf >> 4)) << 9) + ((jf & 15) << 5) + (k & 31)] = f2bf(v);
}

__global__ void k_prep3(const float* __restrict__ P2, unsigned short* __restrict__ B) {
    int tid = blockIdx.x * 256 + threadIdx.x;           // < 4096*288
    int k = tid / 288, cc = tid % 288;
    int k3 = cc / 96, jf = cc % 96;
    float v = fabsf(P2[((1 + k3) * NN + k) * 96 + jf]); // |y2[j][k3][k][f]|, col = k3*96+j*32+f
    B[(((k >> 5) * 18 + (cc >> 4)) << 9) + ((cc & 15) << 5) + (k & 31)] = f2bf(v);
}

// ---------------- Main streaming matmul ----------------
// Block = 512 thr (8 waves). Block owns (mat, 16 rows, all NT*16 cols); waves split K
// into 8x512 chunks. Software-pipelined: A fp32 loads double-buffered (prefetch s+1
// while computing s), all NT B frags staged at iteration top. No barriers in K-loop.
template <int NT>
__global__ __launch_bounds__(512) void k_pass(const float* __restrict__ Umat,
                                              const float* __restrict__ Psi,
                                              const unsigned short* __restrict__ Bfrag,
                                              float* __restrict__ Pout) {
    constexpr int NC = NT * 16;
    int tile = blockIdx.x;
    int mat = blockIdx.y;
    const float* A = (mat == 0) ? Umat : (Psi + (size_t)(mat - 1) * NN * NN);
    int tid = threadIdx.x;
    int wave = tid >> 6, lane = tid & 63;
    int c15 = lane & 15, q = lane >> 4;
    int row = tile * 16 + c15;
    const float* arow = A + (size_t)row * NN + wave * 512 + q * 8;
    const unsigned short* bbase = Bfrag + (size_t)(wave * 16) * NT * 512 + (c15 << 5) + (q << 3);

    floatx4 acc[NT];
#pragma unroll
    for (int t = 0; t < NT; t++) acc[t] = (floatx4){0.f, 0.f, 0.f, 0.f};

    // prologue: A for s=0 in flight
    floatx4 a0 = *(const floatx4*)arow;
    floatx4 a1 = *(const floatx4*)(arow + 4);

    for (int s = 0; s < 16; s++) {
        // stage all B frags for this step (independent loads, L2-resident)
        const unsigned short* bp = bbase + (size_t)s * NT * 512;
        short8 bv[NT];
#pragma unroll
        for (int t = 0; t < NT; t++) bv[t] = *(const short8*)(bp + t * 512);
        // prefetch next A chunk before consuming current
        floatx4 n0 = {}, n1 = {};
        if (s < 15) {
            n0 = *(const floatx4*)(arow + (s + 1) * 32);
            n1 = *(const floatx4*)(arow + (s + 1) * 32 + 4);
        }
        short8 av;
        av[0] = f2bf(a0[0]); av[1] = f2bf(a0[1]); av[2] = f2bf(a0[2]); av[3] = f2bf(a0[3]);
        av[4] = f2bf(a1[0]); av[5] = f2bf(a1[1]); av[6] = f2bf(a1[2]); av[7] = f2bf(a1[3]);
        bf16x8 ab = __builtin_bit_cast(bf16x8, av);
#pragma unroll
        for (int t = 0; t < NT; t++)
            acc[t] = __builtin_amdgcn_mfma_f32_16x16x32_bf16(
                ab, __builtin_bit_cast(bf16x8, bv[t]), acc[t], 0, 0, 0);
        a0 = n0; a1 = n1;
    }

    // reduce partial K-sums across 8 waves: two LDS regions, 4 serialization steps
    __shared__ float cs[2][16 * NC];
    int half = wave & 1;
    for (int w2 = 0; w2 < 4; w2++) {
        if ((wave >> 1) == w2) {
#pragma unroll
            for (int t = 0; t < NT; t++)
#pragma unroll
                for (int r = 0; r < 4; r++) {
                    int idx = (q * 4 + r) * NC + t * 16 + c15;
                    if (w2 == 0) cs[half][idx] = acc[t][r];
                    else cs[half][idx] += acc[t][r];
                }
        }
        __syncthreads();
    }
    float* orow = Pout + ((size_t)mat * NN + (size_t)tile * 16) * NC;
    for (int i = tid; i < 16 * NC; i += 512) orow[i] = cs[0][i] + cs[1][i];
}

// ---------------- GAT stage ----------------
// Fused h + attention logits: one wave per (g,n); lane = head*32+outfeat.
__global__ void k_hes(const float* __restrict__ P1, const float* __restrict__ P2,
                      const float* __restrict__ P3, const float* __restrict__ gatW,
                      const float* __restrict__ attS, const float* __restrict__ attD,
                      float* __restrict__ h, float* __restrict__ es,
                      float* __restrict__ ed) {
    int w = (blockIdx.x * 256 + threadIdx.x) >> 6;  // exactly 13*4096 waves
    int lane = threadIdx.x & 63;
    int g = w >> 12, n = w & 4095;
    const float* crow;
    if (g == 0) crow = P1 + (size_t)n * FF;
    else if (g <= 3) crow = P2 + (size_t)n * 96 + (g - 1) * 32;
    else {
        int j = (g - 4) / 3, k3 = (g - 4) % 3;
        crow = P3 + (size_t)n * 288 + k3 * 96 + j * 32;
    }
    const float* wcol = gatW + g * (32 * 64) + lane;
    float a = 0.f;
#pragma unroll
    for (int f = 0; f < 32; f++) a += crow[f] * wcol[f * 64];
    h[(size_t)w * 64 + lane] = a;
    float vs = a * attS[g * 64 + lane];
    float vd = a * attD[g * 64 + lane];
#pragma unroll
    for (int off = 16; off >= 1; off >>= 1) {
        vs += __shfl_down(vs, off, 32);
        vd += __shfl_down(vd, off, 32);
    }
    if ((lane & 31) == 0) {
        es[w * 2 + (lane >> 5)] = vs;
        ed[w * 2 + (lane >> 5)] = vd;
    }
}

// CSR build over dst (self-loops appended as nodes)
__global__ void k_hist(const int* __restrict__ ei, int* __restrict__ cnt) {
    int e = blockIdx.x * 256 + threadIdx.x;  // exactly EE+NN
    int d = (e < EE) ? ei[EE + e] : (e - EE);
    atomicAdd(&cnt[d], 1);
}

__global__ void k_scan(const int* __restrict__ cnt, int* __restrict__ offs,
                       int* __restrict__ cursor) {
    int lane = threadIdx.x;  // 64 threads, 1 block
    int base = lane * 64;
    int s = 0;
    for (int i = 0; i < 64; i++) s += cnt[base + i];
    int x = s;
    for (int d = 1; d < 64; d <<= 1) {
        int y = __shfl_up(x, d);
        if (lane >= d) x += y;
    }
    int run = x - s;  // exclusive prefix of per-lane totals
    for (int i = 0; i < 64; i++) {
        offs[base + i] = run;
        cursor[base + i] = run;
        run += cnt[base + i];
    }
}

__global__ void k_scatter(const int* __restrict__ ei, int* __restrict__ cursor,
                          int* __restrict__ csr) {
    int e = blockIdx.x * 256 + threadIdx.x;  // exactly EE+NN
    int s, d;
    if (e < EE) { s = ei[e]; d = ei[EE + e]; } else { s = d = e - EE; }
    int pos = atomicAdd(&cursor[d], 1);
    csr[pos] = s;
}

// One wave per (branch g, dst node n); lane = head*32 + feat. Online softmax,
// 2-deep software pipeline on the edge gather chain (csr idx 2 ahead, h/es 1 ahead).
__global__ void k_gat(const float* __restrict__ h, const float* __restrict__ es,
                      const float* __restrict__ ed, const int* __restrict__ offs,
                      const int* __restrict__ cnt, const int* __restrict__ csr,
                      const float* __restrict__ gatb, float* __restrict__ gact) {
    int w = (blockIdx.x * 256 + threadIdx.x) >> 6;  // exactly 13*4096 waves
    int lane = threadIdx.x & 63, hh = lane >> 5;
    int g = w >> 12, n = w & 4095;
    float myed = ed[w * 2 + hh];
    float bias = gatb[g * 64 + lane];
    int start = offs[n], deg = cnt[n];   // deg >= 1 (self-loop)
    const float* hg = h + (size_t)g * NN * 64;
    const float* esg = es + (size_t)g * NN * 2;
    int sA = csr[start];
    int sB = (deg > 1) ? csr[start + 1] : 0;
    float hvA = hg[(size_t)sA * 64 + lane];
    float lgA = esg[sA * 2 + hh];
    float m = -INFINITY, z = 0.f, acc = 0.f;
    for (int i = 0; i < deg; i++) {
        int sC = (i + 2 < deg) ? csr[start + i + 2] : 0;
        float hvB = hg[(size_t)sB * 64 + lane];   // prefetch next (safe index)
        float lgB = esg[sB * 2 + hh];
        float lg = lgA + myed;
        lg = (lg > 0.f) ? lg : 0.2f * lg;               // leaky_relu(0.2)
        float nm = fmaxf(m, lg);
        float sc = __expf(m - nm);
        float we = __expf(lg - nm);
        z = z * sc + we;
        acc = acc * sc + we * hvA;
        m = nm;
        sA = sB; sB = sC; hvA = hvB; lgA = lgB;
    }
    float o = acc / (z + 1e-16f) + bias;
    o = (o > 0.f) ? o : (__expf(o) - 1.f);              // elu
    gact[(size_t)w * 64 + lane] = o;
}

// Branch MLP: feat[n][g*64+k] = elu( gact[g][n][:] . mlpW[g][:,k] + mlpb[g][k] )
__global__ void k_mlp(const float* __restrict__ gact, const float* __restrict__ mlpW,
                      const float* __restrict__ mlpb, float* __restrict__ feat) {
    int tid = blockIdx.x * 256 + threadIdx.x;  // exactly 13*4096*64
    int g = tid >> 18;
    int n = (tid & ((1 << 18) - 1)) >> 6;
    int k = tid & 63;
    const float* grow = gact + ((size_t)g * NN + n) * 64;
    const float* wc = mlpW + (size_t)g * 64 * 64 + k;
    float a = mlpb[g * 64 + k];
#pragma unroll 8
    for (int i = 0; i < 64; i++) a += grow[i] * wc[i * 64];
    a = (a > 0.f) ? a : (__expf(a) - 1.f);              // elu (pre-head)
    feat[(size_t)n * 832 + g * 64 + k] = a;
}

// Head: logits = feat @ outW + outb, then log_softmax. One wave per node.
__global__ void k_final(const float* __restrict__ feat, const float* __restrict__ oW,
                        const float* __restrict__ ob, float* __restrict__ out) {
    int w = (blockIdx.x * 256 + threadIdx.x) >> 6;  // exactly 4096 waves
    int lane = threadIdx.x & 63;
    float a[10];
#pragma unroll
    for (int c = 0; c < 10; c++) a[c] = 0.f;
    const float* frow = feat + (size_t)w * 832;
#pragma unroll
    for (int i = 0; i < 13; i++) {
        float v = frow[i * 64 + lane];
        const float* wp = oW + (i * 64 + lane) * 10;
#pragma unroll
        for (int c = 0; c < 10; c++) a[c] += v * wp[c];
    }
#pragma unroll
    for (int off = 32; off >= 1; off >>= 1)
#pragma unroll
        for (int c = 0; c < 10; c++) a[c] += __shfl_down(a[c], off);
    if (lane == 0) {
        float m = -INFINITY;
#pragma unroll
        for (int c = 0; c < 10; c++) { a[c] += ob[c]; m = fmaxf(m, a[c]); }
        float s = 0.f;
#pragma unroll
        for (int c = 0; c < 10; c++) s += __expf(a[c] - m);
        float lse = m + __logf(s);
#pragma unroll
        for (int c = 0; c < 10; c++) out[w * 10 + c] = a[c] - lse;
    }
}

extern "C" void kernel_launch(void* const* d_in, const int* in_sizes, int n_in,
                              void* d_out, int out_size, void* d_ws, size_t ws_size,
                              hipStream_t stream) {
    const float* x    = (const float*)d_in[0];
    const int*   ei   = (const int*)d_in[1];
    const float* U    = (const float*)d_in[2];
    const float* psi  = (const float*)d_in[3];
    const float* gatW = (const float*)d_in[4];
    const float* attS = (const float*)d_in[5];
    const float* attD = (const float*)d_in[6];
    const float* gatb = (const float*)d_in[7];
    const float* mlpW = (const float*)d_in[8];
    const float* mlpb = (const float*)d_in[9];
    const float* oW   = (const float*)d_in[10];
    const float* ob   = (const float*)d_in[11];
    float* out = (float*)d_out;

    char* ws = (char*)d_ws;
    size_t off = 0;
    auto alloc = [&](size_t bytes) { char* p = ws + off; off += (bytes + 255) & ~(size_t)255; return p; };
    unsigned short* bf1 = (unsigned short*)alloc((size_t)NN * 32 * 2);
    float* P1           = (float*)alloc((size_t)4 * NN * 32 * 4);
    unsigned short* bf2 = (unsigned short*)alloc((size_t)NN * 96 * 2);
    float* P2           = (float*)alloc((size_t)4 * NN * 96 * 4);
    unsigned short* bf3 = (unsigned short*)alloc((size_t)NN * 288 * 2);
    float* P3           = (float*)alloc((size_t)NN * 288 * 4);
    float* h            = (float*)alloc((size_t)GG * NN * 64 * 4);
    float* es           = (float*)alloc((size_t)GG * NN * 2 * 4);
    float* ed           = (float*)alloc((size_t)GG * NN * 2 * 4);
    int* cnt            = (int*)alloc((size_t)NN * 4);
    int* offs           = (int*)alloc((size_t)NN * 4);
    int* cursor         = (int*)alloc((size_t)NN * 4);
    int* csr            = (int*)alloc((size_t)(EE + NN) * 4);
    float* gact         = (float*)alloc((size_t)GG * NN * 64 * 4);
    float* feat         = (float*)alloc((size_t)NN * 832 * 4);
    (void)ws_size; (void)in_sizes; (void)n_in; (void)out_size;

    // CSR build (independent of scattering passes)
    hipMemsetAsync(cnt, 0, NN * 4, stream);
    k_hist<<<(EE + NN) / 256, 256, 0, stream>>>(ei, cnt);
    k_scan<<<1, 64, 0, stream>>>(cnt, offs, cursor);
    k_scatter<<<(EE + NN) / 256, 256, 0, stream>>>(ei, cursor, csr);

    // Scattering passes
    k_prep1<<<(NN * 32) / 256, 256, 0, stream>>>(x, bf1);
    k_pass<2><<<dim3(NN / 16, 4), 512, 0, stream>>>(U, psi, bf1, P1);
    k_prep2<<<(NN * 96) / 256, 256, 0, stream>>>(P1, bf2);
    k_pass<6><<<dim3(NN / 16, 4), 512, 0, stream>>>(U, psi, bf2, P2);
    k_prep3<<<(NN * 288) / 256, 256, 0, stream>>>(P2, bf3);
    k_pass<18><<<dim3(NN / 16, 1), 512, 0, stream>>>(U, psi, bf3, P3);

    // GAT stage
    k_hes<<<(GG * NN * 64) / 256, 256, 0, stream>>>(P1, P2, P3, gatW, attS, attD, h, es, ed);
    k_gat<<<(GG * NN * 64) / 256, 256, 0, stream>>>(h, es, ed, offs, cnt, csr, gatb, gact);
    k_mlp<<<(GG * NN * 64) / 256, 256, 0, stream>>>(gact, mlpW, mlpb, feat);
    k_final<<<(NN * 64) / 256, 256, 0, stream>>>(feat, oW, ob, out);
}

// Round 3
// 656.440 us; speedup vs baseline: 1.0994x; 1.0209x over previous
//
#include <hip/hip_runtime.h>
#include <hip/hip_bf16.h>

#define NN 4096
#define FF 32
#define EE 65536
#define GG 13

typedef float floatx4 __attribute__((ext_vector_type(4)));
typedef __bf16 bf16x8 __attribute__((ext_vector_type(8)));
typedef short short8 __attribute__((ext_vector_type(8)));

__device__ inline unsigned short f2bf(float f) {
    unsigned u = __float_as_uint(f);
    u += 0x7FFFu + ((u >> 16) & 1u);          // RNE to bf16
    return (unsigned short)(u >> 16);
}

// ---------------- B-fragment prep kernels ----------------
// Bfrag layout: element (ks, t, c, kl) at ((ks*NTOT + t)*512 + c*32 + kl), bf16.
// ks = k/32 (K-step), t = col/16 (n-tile), c = col&15, kl = k&31.
// Lane l of the MFMA wave reads 8 contiguous bf16 at c=l&15, kl=(l>>4)*8 -> dwordx4.

__global__ void k_prep1(const float* __restrict__ x, unsigned short* __restrict__ B) {
    int tid = blockIdx.x * 256 + threadIdx.x;           // < 4096*32
    int k = tid >> 5, col = tid & 31;
    float v = fabsf(x[tid]);
    B[(((k >> 5) * 2 + (col >> 4)) << 9) + ((col & 15) << 5) + (k & 31)] = f2bf(v);
}

__global__ void k_prep2(const float* __restrict__ P1, unsigned short* __restrict__ B) {
    int tid = blockIdx.x * 256 + threadIdx.x;           // < 4096*96
    int k = tid / 96, jf = tid % 96;
    int j = jf >> 5, f = jf & 31;
    float v = fabsf(P1[((1 + j) * NN + k) * FF + f]);   // |y1[j][k][f]|
    B[(((k >> 5) * 6 + (jf >> 4)) << 9) + ((jf & 15) << 5) + (k & 31)] = f2bf(v);
}

__global__ void k_prep3(const float* __restrict__ P2, unsigned short* __restrict__ B) {
    int tid = blockIdx.x * 256 + threadIdx.x;           // < 4096*288
    int k = tid / 288, cc = tid % 288;
    int k3 = cc / 96, jf = cc % 96;
    float v = fabsf(P2[((1 + k3) * NN + k) * 96 + jf]); // |y2[j][k3][k][f]|, col = k3*96+j*32+f
    B[(((k >> 5) * 18 + (cc >> 4)) << 9) + ((cc & 15) << 5) + (k & 31)] = f2bf(v);
}

// ---------------- Pass 1: fp32 A stream + fused bf16 A-frag packing ----------------
// Block = 512 thr (8 waves); block owns (mat, 16 rows, 32 cols); waves split K 8x512.
// Each lane's cvt'd short8 IS an A-fragment -> stored to Apack for passes 2/3.
// Apack layout: [mat][rowtile(256)][ks(128)][r*32+kl] (shorts), mat stride 1<<24.
__global__ __launch_bounds__(512) void k_pass1(const float* __restrict__ Umat,
                                               const float* __restrict__ Psi,
                                               const unsigned short* __restrict__ Bfrag,
                                               float* __restrict__ Pout,
                                               unsigned short* __restrict__ Apack) {
    int tile = blockIdx.x;
    int mat = blockIdx.y;
    const float* A = (mat == 0) ? Umat : (Psi + (size_t)(mat - 1) * NN * NN);
    int tid = threadIdx.x;
    int wave = tid >> 6, lane = tid & 63;
    int c15 = lane & 15, q = lane >> 4;
    const float* arow = A + (size_t)(tile * 16 + c15) * NN + wave * 512 + q * 8;
    const unsigned short* bbase = Bfrag + (size_t)(wave * 16) * 2 * 512 + (c15 << 5) + (q << 3);
    unsigned short* apk = Apack + ((size_t)mat << 24) + (size_t)tile * 65536
                          + (size_t)(wave * 16) * 512 + (c15 << 5) + (q << 3);

    floatx4 acc0 = {0.f,0.f,0.f,0.f}, acc1 = {0.f,0.f,0.f,0.f};
    floatx4 a0 = *(const floatx4*)arow;
    floatx4 a1 = *(const floatx4*)(arow + 4);
    short8 bv0 = *(const short8*)bbase;
    short8 bv1 = *(const short8*)(bbase + 512);

    for (int s = 0; s < 15; s++) {
        // prefetch s+1 (A fp32 + B frags) before consuming s
        floatx4 n0 = *(const floatx4*)(arow + (s + 1) * 32);
        floatx4 n1 = *(const floatx4*)(arow + (s + 1) * 32 + 4);
        const unsigned short* bp = bbase + (size_t)(s + 1) * 2 * 512;
        short8 nb0 = *(const short8*)bp;
        short8 nb1 = *(const short8*)(bp + 512);
        short8 av;
        av[0] = f2bf(a0[0]); av[1] = f2bf(a0[1]); av[2] = f2bf(a0[2]); av[3] = f2bf(a0[3]);
        av[4] = f2bf(a1[0]); av[5] = f2bf(a1[1]); av[6] = f2bf(a1[2]); av[7] = f2bf(a1[3]);
        *(short8*)(apk + s * 512) = av;
        bf16x8 ab = __builtin_bit_cast(bf16x8, av);
        acc0 = __builtin_amdgcn_mfma_f32_16x16x32_bf16(ab, __builtin_bit_cast(bf16x8, bv0), acc0, 0, 0, 0);
        acc1 = __builtin_amdgcn_mfma_f32_16x16x32_bf16(ab, __builtin_bit_cast(bf16x8, bv1), acc1, 0, 0, 0);
        a0 = n0; a1 = n1; bv0 = nb0; bv1 = nb1;
    }
    {   // s = 15
        short8 av;
        av[0] = f2bf(a0[0]); av[1] = f2bf(a0[1]); av[2] = f2bf(a0[2]); av[3] = f2bf(a0[3]);
        av[4] = f2bf(a1[0]); av[5] = f2bf(a1[1]); av[6] = f2bf(a1[2]); av[7] = f2bf(a1[3]);
        *(short8*)(apk + 15 * 512) = av;
        bf16x8 ab = __builtin_bit_cast(bf16x8, av);
        acc0 = __builtin_amdgcn_mfma_f32_16x16x32_bf16(ab, __builtin_bit_cast(bf16x8, bv0), acc0, 0, 0, 0);
        acc1 = __builtin_amdgcn_mfma_f32_16x16x32_bf16(ab, __builtin_bit_cast(bf16x8, bv1), acc1, 0, 0, 0);
    }

    // reduce partial K-sums across 8 waves: two LDS regions, 4 serialization steps
    __shared__ float cs[2][16 * 32];
    int half = wave & 1;
    floatx4 acc[2] = {acc0, acc1};
    for (int w2 = 0; w2 < 4; w2++) {
        if ((wave >> 1) == w2) {
#pragma unroll
            for (int t = 0; t < 2; t++)
#pragma unroll
                for (int r = 0; r < 4; r++) {
                    int idx = (q * 4 + r) * 32 + t * 16 + c15;
                    if (w2 == 0) cs[half][idx] = acc[t][r];
                    else cs[half][idx] += acc[t][r];
                }
        }
        __syncthreads();
    }
    float* orow = Pout + ((size_t)mat * NN + (size_t)tile * 16) * 32;
    for (int i = tid; i < 16 * 32; i += 512) orow[i] = cs[0][i] + cs[1][i];
}

// ---------------- Passes 2/3: pure pre-packed bf16 streamer ----------------
template <int NT, int NTOT>
__global__ __launch_bounds__(512) void k_passP(const unsigned short* __restrict__ Apack,
                                               const unsigned short* __restrict__ Bfrag,
                                               float* __restrict__ Pout) {
    constexpr int NC = NT * 16;
    constexpr int NCTOT = NTOT * 16;
    int tile = blockIdx.x;
    int mat = blockIdx.y;
    int cg = blockIdx.z;
    int tid = threadIdx.x;
    int wave = tid >> 6, lane = tid & 63;
    int c15 = lane & 15, q = lane >> 4;
    const unsigned short* ap = Apack + ((size_t)mat << 24) + (size_t)tile * 65536
                               + (size_t)(wave * 16) * 512 + (c15 << 5) + (q << 3);
    const unsigned short* bbase = Bfrag + (size_t)(wave * 16) * NTOT * 512
                                  + (size_t)(cg * NT) * 512 + (c15 << 5) + (q << 3);

    floatx4 acc[NT];
#pragma unroll
    for (int t = 0; t < NT; t++) acc[t] = (floatx4){0.f, 0.f, 0.f, 0.f};

    short8 af = *(const short8*)ap;
    short8 bv[NT];
#pragma unroll
    for (int t = 0; t < NT; t++) bv[t] = *(const short8*)(bbase + t * 512);

    for (int s = 0; s < 15; s++) {
        short8 af2 = *(const short8*)(ap + (s + 1) * 512);
        short8 bv2[NT];
        const unsigned short* bp = bbase + (size_t)(s + 1) * NTOT * 512;
#pragma unroll
        for (int t = 0; t < NT; t++) bv2[t] = *(const short8*)(bp + t * 512);
        bf16x8 ab = __builtin_bit_cast(bf16x8, af);
#pragma unroll
        for (int t = 0; t < NT; t++)
            acc[t] = __builtin_amdgcn_mfma_f32_16x16x32_bf16(
                ab, __builtin_bit_cast(bf16x8, bv[t]), acc[t], 0, 0, 0);
        af = af2;
#pragma unroll
        for (int t = 0; t < NT; t++) bv[t] = bv2[t];
    }
    {
        bf16x8 ab = __builtin_bit_cast(bf16x8, af);
#pragma unroll
        for (int t = 0; t < NT; t++)
            acc[t] = __builtin_amdgcn_mfma_f32_16x16x32_bf16(
                ab, __builtin_bit_cast(bf16x8, bv[t]), acc[t], 0, 0, 0);
    }

    __shared__ float cs[2][16 * NC];
    int half = wave & 1;
    for (int w2 = 0; w2 < 4; w2++) {
        if ((wave >> 1) == w2) {
#pragma unroll
            for (int t = 0; t < NT; t++)
#pragma unroll
                for (int r = 0; r < 4; r++) {
                    int idx = (q * 4 + r) * NC + t * 16 + c15;
                    if (w2 == 0) cs[half][idx] = acc[t][r];
                    else cs[half][idx] += acc[t][r];
                }
        }
        __syncthreads();
    }
    float* orow = Pout + ((size_t)mat * NN + (size_t)tile * 16) * NCTOT + cg * NC;
    for (int i = tid; i < 16 * NC; i += 512) {
        int r = i / NC, c = i % NC;
        orow[(size_t)r * NCTOT + c] = cs[0][i] + cs[1][i];
    }
}

// ---------------- GAT stage ----------------
// Fused h + attention logits: one wave per (g,n); lane = head*32+outfeat.
__global__ void k_hes(const float* __restrict__ P1, const float* __restrict__ P2,
                      const float* __restrict__ P3, const float* __restrict__ gatW,
                      const float* __restrict__ attS, const float* __restrict__ attD,
                      float* __restrict__ h, float* __restrict__ es,
                      float* __restrict__ ed) {
    int w = (blockIdx.x * 256 + threadIdx.x) >> 6;  // exactly 13*4096 waves
    int lane = threadIdx.x & 63;
    int g = w >> 12, n = w & 4095;
    const float* crow;
    if (g == 0) crow = P1 + (size_t)n * FF;
    else if (g <= 3) crow = P2 + (size_t)n * 96 + (g - 1) * 32;
    else {
        int j = (g - 4) / 3, k3 = (g - 4) % 3;
        crow = P3 + (size_t)n * 288 + k3 * 96 + j * 32;
    }
    const float* wcol = gatW + g * (32 * 64) + lane;
    float a = 0.f;
#pragma unroll
    for (int f = 0; f < 32; f++) a += crow[f] * wcol[f * 64];
    h[(size_t)w * 64 + lane] = a;
    float vs = a * attS[g * 64 + lane];
    float vd = a * attD[g * 64 + lane];
#pragma unroll
    for (int off = 16; off >= 1; off >>= 1) {
        vs += __shfl_down(vs, off, 32);
        vd += __shfl_down(vd, off, 32);
    }
    if ((lane & 31) == 0) {
        es[w * 2 + (lane >> 5)] = vs;
        ed[w * 2 + (lane >> 5)] = vd;
    }
}

// CSR build over dst (self-loops appended as nodes)
__global__ void k_hist(const int* __restrict__ ei, int* __restrict__ cnt) {
    int e = blockIdx.x * 256 + threadIdx.x;  // exactly EE+NN
    int d = (e < EE) ? ei[EE + e] : (e - EE);
    atomicAdd(&cnt[d], 1);
}

__global__ void k_scan(const int* __restrict__ cnt, int* __restrict__ offs,
                       int* __restrict__ cursor) {
    int lane = threadIdx.x;  // 64 threads, 1 block
    int base = lane * 64;
    int s = 0;
    for (int i = 0; i < 64; i++) s += cnt[base + i];
    int x = s;
    for (int d = 1; d < 64; d <<= 1) {
        int y = __shfl_up(x, d);
        if (lane >= d) x += y;
    }
    int run = x - s;  // exclusive prefix of per-lane totals
    for (int i = 0; i < 64; i++) {
        offs[base + i] = run;
        cursor[base + i] = run;
        run += cnt[base + i];
    }
}

__global__ void k_scatter(const int* __restrict__ ei, int* __restrict__ cursor,
                          int* __restrict__ csr) {
    int e = blockIdx.x * 256 + threadIdx.x;  // exactly EE+NN
    int s, d;
    if (e < EE) { s = ei[e]; d = ei[EE + e]; } else { s = d = e - EE; }
    int pos = atomicAdd(&cursor[d], 1);
    csr[pos] = s;
}

// One wave per (branch g, dst node n); lane = head*32 + feat. Online softmax,
// 2-deep software pipeline on the edge gather chain.
__global__ void k_gat(const float* __restrict__ h, const float* __restrict__ es,
                      const float* __restrict__ ed, const int* __restrict__ offs,
                      const int* __restrict__ cnt, const int* __restrict__ csr,
                      const float* __restrict__ gatb, float* __restrict__ gact) {
    int w = (blockIdx.x * 256 + threadIdx.x) >> 6;  // exactly 13*4096 waves
    int lane = threadIdx.x & 63, hh = lane >> 5;
    int g = w >> 12, n = w & 4095;
    float myed = ed[w * 2 + hh];
    float bias = gatb[g * 64 + lane];
    int start = offs[n], deg = cnt[n];   // deg >= 1 (self-loop)
    const float* hg = h + (size_t)g * NN * 64;
    const float* esg = es + (size_t)g * NN * 2;
    int sA = csr[start];
    int sB = (deg > 1) ? csr[start + 1] : 0;
    float hvA = hg[(size_t)sA * 64 + lane];
    float lgA = esg[sA * 2 + hh];
    float m = -INFINITY, z = 0.f, acc = 0.f;
    for (int i = 0; i < deg; i++) {
        int sC = (i + 2 < deg) ? csr[start + i + 2] : 0;
        float hvB = hg[(size_t)sB * 64 + lane];   // prefetch next (safe index)
        float lgB = esg[sB * 2 + hh];
        float lg = lgA + myed;
        lg = (lg > 0.f) ? lg : 0.2f * lg;               // leaky_relu(0.2)
        float nm = fmaxf(m, lg);
        float sc = __expf(m - nm);
        float we = __expf(lg - nm);
        z = z * sc + we;
        acc = acc * sc + we * hvA;
        m = nm;
        sA = sB; sB = sC; hvA = hvB; lgA = lgB;
    }
    float o = acc / (z + 1e-16f) + bias;
    o = (o > 0.f) ? o : (__expf(o) - 1.f);              // elu
    gact[(size_t)w * 64 + lane] = o;
}

// Branch MLP: feat[n][g*64+k] = elu( gact[g][n][:] . mlpW[g][:,k] + mlpb[g][k] )
__global__ void k_mlp(const float* __restrict__ gact, const float* __restrict__ mlpW,
                      const float* __restrict__ mlpb, float* __restrict__ feat) {
    int tid = blockIdx.x * 256 + threadIdx.x;  // exactly 13*4096*64
    int g = tid >> 18;
    int n = (tid & ((1 << 18) - 1)) >> 6;
    int k = tid & 63;
    const float* grow = gact + ((size_t)g * NN + n) * 64;
    const float* wc = mlpW + (size_t)g * 64 * 64 + k;
    float a = mlpb[g * 64 + k];
#pragma unroll 8
    for (int i = 0; i < 64; i++) a += grow[i] * wc[i * 64];
    a = (a > 0.f) ? a : (__expf(a) - 1.f);              // elu (pre-head)
    feat[(size_t)n * 832 + g * 64 + k] = a;
}

// Head: logits = feat @ outW + outb, then log_softmax. One wave per node.
__global__ void k_final(const float* __restrict__ feat, const float* __restrict__ oW,
                        const float* __restrict__ ob, float* __restrict__ out) {
    int w = (blockIdx.x * 256 + threadIdx.x) >> 6;  // exactly 4096 waves
    int lane = threadIdx.x & 63;
    float a[10];
#pragma unroll
    for (int c = 0; c < 10; c++) a[c] = 0.f;
    const float* frow = feat + (size_t)w * 832;
#pragma unroll
    for (int i = 0; i < 13; i++) {
        float v = frow[i * 64 + lane];
        const float* wp = oW + (i * 64 + lane) * 10;
#pragma unroll
        for (int c = 0; c < 10; c++) a[c] += v * wp[c];
    }
#pragma unroll
    for (int off = 32; off >= 1; off >>= 1)
#pragma unroll
        for (int c = 0; c < 10; c++) a[c] += __shfl_down(a[c], off);
    if (lane == 0) {
        float m = -INFINITY;
#pragma unroll
        for (int c = 0; c < 10; c++) { a[c] += ob[c]; m = fmaxf(m, a[c]); }
        float s = 0.f;
#pragma unroll
        for (int c = 0; c < 10; c++) s += __expf(a[c] - m);
        float lse = m + __logf(s);
#pragma unroll
        for (int c = 0; c < 10; c++) out[w * 10 + c] = a[c] - lse;
    }
}

extern "C" void kernel_launch(void* const* d_in, const int* in_sizes, int n_in,
                              void* d_out, int out_size, void* d_ws, size_t ws_size,
                              hipStream_t stream) {
    const float* x    = (const float*)d_in[0];
    const int*   ei   = (const int*)d_in[1];
    const float* U    = (const float*)d_in[2];
    const float* psi  = (const float*)d_in[3];
    const float* gatW = (const float*)d_in[4];
    const float* attS = (const float*)d_in[5];
    const float* attD = (const float*)d_in[6];
    const float* gatb = (const float*)d_in[7];
    const float* mlpW = (const float*)d_in[8];
    const float* mlpb = (const float*)d_in[9];
    const float* oW   = (const float*)d_in[10];
    const float* ob   = (const float*)d_in[11];
    float* out = (float*)d_out;

    char* ws = (char*)d_ws;
    size_t off = 0;
    auto alloc = [&](size_t bytes) { char* p = ws + off; off += (bytes + 255) & ~(size_t)255; return p; };
    unsigned short* Apack = (unsigned short*)alloc((size_t)4 * NN * NN * 2);  // 128 MB bf16 A-frags
    unsigned short* bf1 = (unsigned short*)alloc((size_t)NN * 32 * 2);
    float* P1           = (float*)alloc((size_t)4 * NN * 32 * 4);
    unsigned short* bf2 = (unsigned short*)alloc((size_t)NN * 96 * 2);
    float* P2           = (float*)alloc((size_t)4 * NN * 96 * 4);
    unsigned short* bf3 = (unsigned short*)alloc((size_t)NN * 288 * 2);
    float* P3           = (float*)alloc((size_t)NN * 288 * 4);
    float* h            = (float*)alloc((size_t)GG * NN * 64 * 4);
    float* es           = (float*)alloc((size_t)GG * NN * 2 * 4);
    float* ed           = (float*)alloc((size_t)GG * NN * 2 * 4);
    int* cnt            = (int*)alloc((size_t)NN * 4);
    int* offs           = (int*)alloc((size_t)NN * 4);
    int* cursor         = (int*)alloc((size_t)NN * 4);
    int* csr            = (int*)alloc((size_t)(EE + NN) * 4);
    float* gact         = (float*)alloc((size_t)GG * NN * 64 * 4);
    float* feat         = (float*)alloc((size_t)NN * 832 * 4);
    (void)ws_size; (void)in_sizes; (void)n_in; (void)out_size;

    // CSR build (independent of scattering passes)
    hipMemsetAsync(cnt, 0, NN * 4, stream);
    k_hist<<<(EE + NN) / 256, 256, 0, stream>>>(ei, cnt);
    k_scan<<<1, 64, 0, stream>>>(cnt, offs, cursor);
    k_scatter<<<(EE + NN) / 256, 256, 0, stream>>>(ei, cursor, csr);

    // Scattering passes
    k_prep1<<<(NN * 32) / 256, 256, 0, stream>>>(x, bf1);
    k_pass1<<<dim3(NN / 16, 4), 512, 0, stream>>>(U, psi, bf1, P1, Apack);
    k_prep2<<<(NN * 96) / 256, 256, 0, stream>>>(P1, bf2);
    k_passP<6, 6><<<dim3(NN / 16, 4, 1), 512, 0, stream>>>(Apack, bf2, P2);
    k_prep3<<<(NN * 288) / 256, 256, 0, stream>>>(P2, bf3);
    k_passP<6, 18><<<dim3(NN / 16, 1, 3), 512, 0, stream>>>(Apack, bf3, P3);

    // GAT stage
    k_hes<<<(GG * NN * 64) / 256, 256, 0, stream>>>(P1, P2, P3, gatW, attS, attD, h, es, ed);
    k_gat<<<(GG * NN * 64) / 256, 256, 0, stream>>>(h, es, ed, offs, cnt, csr, gatb, gact);
    k_mlp<<<(GG * NN * 64) / 256, 256, 0, stream>>>(gact, mlpW, mlpb, feat);
    k_final<<<(NN * 64) / 256, 256, 0, stream>>>(feat, oW, ob, out);
}

// Round 4
// 650.658 us; speedup vs baseline: 1.1091x; 1.0089x over previous
//
#include <hip/hip_runtime.h>
#include <hip/hip_bf16.h>

#define NN 4096
#define FF 32
#define EE 65536
#define GG 13

typedef float floatx4 __attribute__((ext_vector_type(4)));
typedef __bf16 bf16x8 __attribute__((ext_vector_type(8)));
typedef short short8 __attribute__((ext_vector_type(8)));

__device__ inline unsigned short f2bf(float f) {
    unsigned u = __float_as_uint(f);
    u += 0x7FFFu + ((u >> 16) & 1u);          // RNE to bf16
    return (unsigned short)(u >> 16);
}

// ---------------- B-fragment prep kernels ----------------
// Bfrag layout: element (ks, t, c, kl) at ((ks*NTOT + t)*512 + c*32 + kl), bf16.
// ks = k/32 (K-step), t = col/16 (n-tile), c = col&15, kl = k&31.
// Lane l reads 8 contiguous bf16 at c=l&15, kl=(l>>4)*8 -> per-instr 1KB contiguous.

__global__ void k_prep1(const float* __restrict__ x, unsigned short* __restrict__ B) {
    int tid = blockIdx.x * 256 + threadIdx.x;           // < 4096*32
    int k = tid >> 5, col = tid & 31;
    float v = fabsf(x[tid]);
    B[(((k >> 5) * 2 + (col >> 4)) << 9) + ((col & 15) << 5) + (k & 31)] = f2bf(v);
}

__global__ void k_prep2(const float* __restrict__ P1, unsigned short* __restrict__ B) {
    int tid = blockIdx.x * 256 + threadIdx.x;           // < 4096*96
    int k = tid / 96, jf = tid % 96;
    int j = jf >> 5, f = jf & 31;
    float v = fabsf(P1[((1 + j) * NN + k) * FF + f]);   // |y1[j][k][f]|
    B[(((k >> 5) * 6 + (jf >> 4)) << 9) + ((jf & 15) << 5) + (k & 31)] = f2bf(v);
}

__global__ void k_prep3(const float* __restrict__ P2, unsigned short* __restrict__ B) {
    int tid = blockIdx.x * 256 + threadIdx.x;           // < 4096*288
    int k = tid / 288, cc = tid % 288;
    int k3 = cc / 96, jf = cc % 96;
    float v = fabsf(P2[((1 + k3) * NN + k) * 96 + jf]); // |y2[j][k3][k][f]|, col = k3*96+j*32+f
    B[(((k >> 5) * 18 + (cc >> 4)) << 9) + ((cc & 15) << 5) + (k & 31)] = f2bf(v);
}

// ---------------- Pass 1: LDS-staged fp32 A stream + fused bf16 A-frag packing ----
// Block = 512 thr (8 waves), grid (256 tiles, 4 mats). Per chunk: 16 rows x 512 K
// fp32 (32 KB) staged via CONTIGUOUS float4 loads (1 KB/wave/instr) prefetched into
// registers during previous chunk's compute, then LDS (row pad +16B -> conflict-free
// b128 reads). Waves split the chunk's 16 K-steps; cvt'd short8 IS an A-fragment ->
// stored to Apack (1KB-contiguous) for passes 2/3.
// Apack layout: [mat][tile(256)][ks(128)][c15*32 + q*8 + j] shorts, mat stride 1<<24.
__global__ __launch_bounds__(512) void k_pass1(const float* __restrict__ Umat,
                                               const float* __restrict__ Psi,
                                               const unsigned short* __restrict__ Bfrag,
                                               float* __restrict__ Pout,
                                               unsigned short* __restrict__ Apack) {
    __shared__ float abuf[16 * 516];          // 16 rows x (512 + 4 pad) fp32 = 33 KB
    __shared__ float cs[2][16 * 32];
    int tile = blockIdx.x, mat = blockIdx.y;
    const float* A = (mat == 0) ? Umat : (Psi + (size_t)(mat - 1) * NN * NN);
    int tid = threadIdx.x;
    int wave = tid >> 6, lane = tid & 63;
    int c15 = lane & 15, q = lane >> 4;

    const float* atile = A + (size_t)tile * 16 * NN;
    const unsigned short* bbase = Bfrag + (c15 << 5) + (q << 3);
    unsigned short* apk = Apack + ((size_t)mat << 24) + (size_t)tile * 65536
                          + (c15 << 5) + (q << 3);

    floatx4 acc0 = {0.f,0.f,0.f,0.f}, acc1 = {0.f,0.f,0.f,0.f};
    floatx4 v[4];

    // prologue: stage chunk 0 (each wave: 4 x 1KB contiguous segments)
#pragma unroll
    for (int i = 0; i < 4; i++) {
        int seg = wave * 4 + i, row = seg >> 1, half = seg & 1;
        v[i] = *(const floatx4*)(atile + (size_t)row * NN + half * 256 + lane * 4);
    }
#pragma unroll
    for (int i = 0; i < 4; i++) {
        int seg = wave * 4 + i, row = seg >> 1, half = seg & 1;
        *(floatx4*)(abuf + row * 516 + half * 256 + lane * 4) = v[i];
    }
    __syncthreads();

    for (int chunk = 0; chunk < 8; chunk++) {
        if (chunk < 7) {   // prefetch next chunk into registers (in flight over compute)
#pragma unroll
            for (int i = 0; i < 4; i++) {
                int seg = wave * 4 + i, row = seg >> 1, half = seg & 1;
                v[i] = *(const floatx4*)(atile + (size_t)row * NN + (chunk + 1) * 512
                                         + half * 256 + lane * 4);
            }
        }
#pragma unroll
        for (int t = 0; t < 2; t++) {
            int ksl = wave * 2 + t;            // this wave's K-step within the chunk
            int ksg = chunk * 16 + ksl;        // global K-step
            short8 bv0 = *(const short8*)(bbase + (size_t)(ksg * 2 + 0) * 512);
            short8 bv1 = *(const short8*)(bbase + (size_t)(ksg * 2 + 1) * 512);
            const float* lp = abuf + c15 * 516 + ksl * 32 + q * 8;
            floatx4 f0 = *(const floatx4*)lp;
            floatx4 f1 = *(const floatx4*)(lp + 4);
            short8 av;
            av[0]=f2bf(f0[0]); av[1]=f2bf(f0[1]); av[2]=f2bf(f0[2]); av[3]=f2bf(f0[3]);
            av[4]=f2bf(f1[0]); av[5]=f2bf(f1[1]); av[6]=f2bf(f1[2]); av[7]=f2bf(f1[3]);
            *(short8*)(apk + (size_t)ksg * 512) = av;
            bf16x8 ab = __builtin_bit_cast(bf16x8, av);
            acc0 = __builtin_amdgcn_mfma_f32_16x16x32_bf16(ab, __builtin_bit_cast(bf16x8, bv0), acc0, 0, 0, 0);
            acc1 = __builtin_amdgcn_mfma_f32_16x16x32_bf16(ab, __builtin_bit_cast(bf16x8, bv1), acc1, 0, 0, 0);
        }
        __syncthreads();                       // all waves done reading abuf
        if (chunk < 7) {
#pragma unroll
            for (int i = 0; i < 4; i++) {
                int seg = wave * 4 + i, row = seg >> 1, half = seg & 1;
                *(floatx4*)(abuf + row * 516 + half * 256 + lane * 4) = v[i];
            }
            __syncthreads();                   // abuf refilled for next chunk
        }
    }

    // reduce partial K-sums across 8 waves: two LDS regions, 4 serialization steps
    int half = wave & 1;
    floatx4 acc[2] = {acc0, acc1};
    for (int w2 = 0; w2 < 4; w2++) {
        if ((wave >> 1) == w2) {
#pragma unroll
            for (int t = 0; t < 2; t++)
#pragma unroll
                for (int r = 0; r < 4; r++) {
                    int idx = (q * 4 + r) * 32 + t * 16 + c15;
                    if (w2 == 0) cs[half][idx] = acc[t][r];
                    else cs[half][idx] += acc[t][r];
                }
        }
        __syncthreads();
    }
    float* orow = Pout + ((size_t)mat * NN + (size_t)tile * 16) * 32;
    for (int i = tid; i < 16 * 32; i += 512) orow[i] = cs[0][i] + cs[1][i];
}

// ---------------- Passes 2/3: pure pre-packed bf16 streamer ----------------
template <int NT, int NTOT>
__global__ __launch_bounds__(512) void k_passP(const unsigned short* __restrict__ Apack,
                                               const unsigned short* __restrict__ Bfrag,
                                               float* __restrict__ Pout) {
    constexpr int NC = NT * 16;
    constexpr int NCTOT = NTOT * 16;
    int tile = blockIdx.x;
    int mat = blockIdx.y;
    int cg = blockIdx.z;
    int tid = threadIdx.x;
    int wave = tid >> 6, lane = tid & 63;
    int c15 = lane & 15, q = lane >> 4;
    const unsigned short* ap = Apack + ((size_t)mat << 24) + (size_t)tile * 65536
                               + (size_t)(wave * 16) * 512 + (c15 << 5) + (q << 3);
    const unsigned short* bbase = Bfrag + (size_t)(wave * 16) * NTOT * 512
                                  + (size_t)(cg * NT) * 512 + (c15 << 5) + (q << 3);

    floatx4 acc[NT];
#pragma unroll
    for (int t = 0; t < NT; t++) acc[t] = (floatx4){0.f, 0.f, 0.f, 0.f};

    short8 af = *(const short8*)ap;
    short8 bv[NT];
#pragma unroll
    for (int t = 0; t < NT; t++) bv[t] = *(const short8*)(bbase + t * 512);

    for (int s = 0; s < 15; s++) {
        short8 af2 = *(const short8*)(ap + (s + 1) * 512);
        short8 bv2[NT];
        const unsigned short* bp = bbase + (size_t)(s + 1) * NTOT * 512;
#pragma unroll
        for (int t = 0; t < NT; t++) bv2[t] = *(const short8*)(bp + t * 512);
        bf16x8 ab = __builtin_bit_cast(bf16x8, af);
#pragma unroll
        for (int t = 0; t < NT; t++)
            acc[t] = __builtin_amdgcn_mfma_f32_16x16x32_bf16(
                ab, __builtin_bit_cast(bf16x8, bv[t]), acc[t], 0, 0, 0);
        af = af2;
#pragma unroll
        for (int t = 0; t < NT; t++) bv[t] = bv2[t];
    }
    {
        bf16x8 ab = __builtin_bit_cast(bf16x8, af);
#pragma unroll
        for (int t = 0; t < NT; t++)
            acc[t] = __builtin_amdgcn_mfma_f32_16x16x32_bf16(
                ab, __builtin_bit_cast(bf16x8, bv[t]), acc[t], 0, 0, 0);
    }

    __shared__ float cs[2][16 * NC];
    int half = wave & 1;
    for (int w2 = 0; w2 < 4; w2++) {
        if ((wave >> 1) == w2) {
#pragma unroll
            for (int t = 0; t < NT; t++)
#pragma unroll
                for (int r = 0; r < 4; r++) {
                    int idx = (q * 4 + r) * NC + t * 16 + c15;
                    if (w2 == 0) cs[half][idx] = acc[t][r];
                    else cs[half][idx] += acc[t][r];
                }
        }
        __syncthreads();
    }
    float* orow = Pout + ((size_t)mat * NN + (size_t)tile * 16) * NCTOT + cg * NC;
    for (int i = tid; i < 16 * NC; i += 512) {
        int r = i / NC, c = i % NC;
        orow[(size_t)r * NCTOT + c] = cs[0][i] + cs[1][i];
    }
}

// ---------------- GAT stage ----------------
// Fused h + attention logits: one wave per (g,n); lane = head*32+outfeat.
__global__ void k_hes(const float* __restrict__ P1, const float* __restrict__ P2,
                      const float* __restrict__ P3, const float* __restrict__ gatW,
                      const float* __restrict__ attS, const float* __restrict__ attD,
                      float* __restrict__ h, float* __restrict__ es,
                      float* __restrict__ ed) {
    int w = (blockIdx.x * 256 + threadIdx.x) >> 6;  // exactly 13*4096 waves
    int lane = threadIdx.x & 63;
    int g = w >> 12, n = w & 4095;
    const float* crow;
    if (g == 0) crow = P1 + (size_t)n * FF;
    else if (g <= 3) crow = P2 + (size_t)n * 96 + (g - 1) * 32;
    else {
        int j = (g - 4) / 3, k3 = (g - 4) % 3;
        crow = P3 + (size_t)n * 288 + k3 * 96 + j * 32;
    }
    const float* wcol = gatW + g * (32 * 64) + lane;
    float a = 0.f;
#pragma unroll
    for (int f = 0; f < 32; f++) a += crow[f] * wcol[f * 64];
    h[(size_t)w * 64 + lane] = a;
    float vs = a * attS[g * 64 + lane];
    float vd = a * attD[g * 64 + lane];
#pragma unroll
    for (int off = 16; off >= 1; off >>= 1) {
        vs += __shfl_down(vs, off, 32);
        vd += __shfl_down(vd, off, 32);
    }
    if ((lane & 31) == 0) {
        es[w * 2 + (lane >> 5)] = vs;
        ed[w * 2 + (lane >> 5)] = vd;
    }
}

// CSR build over dst (self-loops appended as nodes)
__global__ void k_hist(const int* __restrict__ ei, int* __restrict__ cnt) {
    int e = blockIdx.x * 256 + threadIdx.x;  // exactly EE+NN
    int d = (e < EE) ? ei[EE + e] : (e - EE);
    atomicAdd(&cnt[d], 1);
}

__global__ void k_scan(const int* __restrict__ cnt, int* __restrict__ offs,
                       int* __restrict__ cursor) {
    int lane = threadIdx.x;  // 64 threads, 1 block
    int base = lane * 64;
    int s = 0;
    for (int i = 0; i < 64; i++) s += cnt[base + i];
    int x = s;
    for (int d = 1; d < 64; d <<= 1) {
        int y = __shfl_up(x, d);
        if (lane >= d) x += y;
    }
    int run = x - s;  // exclusive prefix of per-lane totals
    for (int i = 0; i < 64; i++) {
        offs[base + i] = run;
        cursor[base + i] = run;
        run += cnt[base + i];
    }
}

__global__ void k_scatter(const int* __restrict__ ei, int* __restrict__ cursor,
                          int* __restrict__ csr) {
    int e = blockIdx.x * 256 + threadIdx.x;  // exactly EE+NN
    int s, d;
    if (e < EE) { s = ei[e]; d = ei[EE + e]; } else { s = d = e - EE; }
    int pos = atomicAdd(&cursor[d], 1);
    csr[pos] = s;
}

// One wave per (branch g, dst node n); lane = head*32 + feat. Online softmax,
// 2-deep software pipeline on the edge gather chain.
__global__ void k_gat(const float* __restrict__ h, const float* __restrict__ es,
                      const float* __restrict__ ed, const int* __restrict__ offs,
                      const int* __restrict__ cnt, const int* __restrict__ csr,
                      const float* __restrict__ gatb, float* __restrict__ gact) {
    int w = (blockIdx.x * 256 + threadIdx.x) >> 6;  // exactly 13*4096 waves
    int lane = threadIdx.x & 63, hh = lane >> 5;
    int g = w >> 12, n = w & 4095;
    float myed = ed[w * 2 + hh];
    float bias = gatb[g * 64 + lane];
    int start = offs[n], deg = cnt[n];   // deg >= 1 (self-loop)
    const float* hg = h + (size_t)g * NN * 64;
    const float* esg = es + (size_t)g * NN * 2;
    int sA = csr[start];
    int sB = (deg > 1) ? csr[start + 1] : 0;
    float hvA = hg[(size_t)sA * 64 + lane];
    float lgA = esg[sA * 2 + hh];
    float m = -INFINITY, z = 0.f, acc = 0.f;
    for (int i = 0; i < deg; i++) {
        int sC = (i + 2 < deg) ? csr[start + i + 2] : 0;
        float hvB = hg[(size_t)sB * 64 + lane];   // prefetch next (safe index)
        float lgB = esg[sB * 2 + hh];
        float lg = lgA + myed;
        lg = (lg > 0.f) ? lg : 0.2f * lg;               // leaky_relu(0.2)
        float nm = fmaxf(m, lg);
        float sc = __expf(m - nm);
        float we = __expf(lg - nm);
        z = z * sc + we;
        acc = acc * sc + we * hvA;
        m = nm;
        sA = sB; sB = sC; hvA = hvB; lgA = lgB;
    }
    float o = acc / (z + 1e-16f) + bias;
    o = (o > 0.f) ? o : (__expf(o) - 1.f);              // elu
    gact[(size_t)w * 64 + lane] = o;
}

// Branch MLP: feat[n][g*64+k] = elu( gact[g][n][:] . mlpW[g][:,k] + mlpb[g][k] )
__global__ void k_mlp(const float* __restrict__ gact, const float* __restrict__ mlpW,
                      const float* __restrict__ mlpb, float* __restrict__ feat) {
    int tid = blockIdx.x * 256 + threadIdx.x;  // exactly 13*4096*64
    int g = tid >> 18;
    int n = (tid & ((1 << 18) - 1)) >> 6;
    int k = tid & 63;
    const float* grow = gact + ((size_t)g * NN + n) * 64;
    const float* wc = mlpW + (size_t)g * 64 * 64 + k;
    float a = mlpb[g * 64 + k];
#pragma unroll 8
    for (int i = 0; i < 64; i++) a += grow[i] * wc[i * 64];
    a = (a > 0.f) ? a : (__expf(a) - 1.f);              // elu (pre-head)
    feat[(size_t)n * 832 + g * 64 + k] = a;
}

// Head: logits = feat @ outW + outb, then log_softmax. One wave per node.
__global__ void k_final(const float* __restrict__ feat, const float* __restrict__ oW,
                        const float* __restrict__ ob, float* __restrict__ out) {
    int w = (blockIdx.x * 256 + threadIdx.x) >> 6;  // exactly 4096 waves
    int lane = threadIdx.x & 63;
    float a[10];
#pragma unroll
    for (int c = 0; c < 10; c++) a[c] = 0.f;
    const float* frow = feat + (size_t)w * 832;
#pragma unroll
    for (int i = 0; i < 13; i++) {
        float v = frow[i * 64 + lane];
        const float* wp = oW + (i * 64 + lane) * 10;
#pragma unroll
        for (int c = 0; c < 10; c++) a[c] += v * wp[c];
    }
#pragma unroll
    for (int off = 32; off >= 1; off >>= 1)
#pragma unroll
        for (int c = 0; c < 10; c++) a[c] += __shfl_down(a[c], off);
    if (lane == 0) {
        float m = -INFINITY;
#pragma unroll
        for (int c = 0; c < 10; c++) { a[c] += ob[c]; m = fmaxf(m, a[c]); }
        float s = 0.f;
#pragma unroll
        for (int c = 0; c < 10; c++) s += __expf(a[c] - m);
        float lse = m + __logf(s);
#pragma unroll
        for (int c = 0; c < 10; c++) out[w * 10 + c] = a[c] - lse;
    }
}

extern "C" void kernel_launch(void* const* d_in, const int* in_sizes, int n_in,
                              void* d_out, int out_size, void* d_ws, size_t ws_size,
                              hipStream_t stream) {
    const float* x    = (const float*)d_in[0];
    const int*   ei   = (const int*)d_in[1];
    const float* U    = (const float*)d_in[2];
    const float* psi  = (const float*)d_in[3];
    const float* gatW = (const float*)d_in[4];
    const float* attS = (const float*)d_in[5];
    const float* attD = (const float*)d_in[6];
    const float* gatb = (const float*)d_in[7];
    const float* mlpW = (const float*)d_in[8];
    const float* mlpb = (const float*)d_in[9];
    const float* oW   = (const float*)d_in[10];
    const float* ob   = (const float*)d_in[11];
    float* out = (float*)d_out;

    char* ws = (char*)d_ws;
    size_t off = 0;
    auto alloc = [&](size_t bytes) { char* p = ws + off; off += (bytes + 255) & ~(size_t)255; return p; };
    unsigned short* Apack = (unsigned short*)alloc((size_t)4 * NN * NN * 2);  // 128 MB bf16 A-frags
    unsigned short* bf1 = (unsigned short*)alloc((size_t)NN * 32 * 2);
    float* P1           = (float*)alloc((size_t)4 * NN * 32 * 4);
    unsigned short* bf2 = (unsigned short*)alloc((size_t)NN * 96 * 2);
    float* P2           = (float*)alloc((size_t)4 * NN * 96 * 4);
    unsigned short* bf3 = (unsigned short*)alloc((size_t)NN * 288 * 2);
    float* P3           = (float*)alloc((size_t)NN * 288 * 4);
    float* h            = (float*)alloc((size_t)GG * NN * 64 * 4);
    float* es           = (float*)alloc((size_t)GG * NN * 2 * 4);
    float* ed           = (float*)alloc((size_t)GG * NN * 2 * 4);
    int* cnt            = (int*)alloc((size_t)NN * 4);
    int* offs           = (int*)alloc((size_t)NN * 4);
    int* cursor         = (int*)alloc((size_t)NN * 4);
    int* csr            = (int*)alloc((size_t)(EE + NN) * 4);
    float* gact         = (float*)alloc((size_t)GG * NN * 64 * 4);
    float* feat         = (float*)alloc((size_t)NN * 832 * 4);
    (void)ws_size; (void)in_sizes; (void)n_in; (void)out_size;

    // CSR build (independent of scattering passes)
    hipMemsetAsync(cnt, 0, NN * 4, stream);
    k_hist<<<(EE + NN) / 256, 256, 0, stream>>>(ei, cnt);
    k_scan<<<1, 64, 0, stream>>>(cnt, offs, cursor);
    k_scatter<<<(EE + NN) / 256, 256, 0, stream>>>(ei, cursor, csr);

    // Scattering passes
    k_prep1<<<(NN * 32) / 256, 256, 0, stream>>>(x, bf1);
    k_pass1<<<dim3(NN / 16, 4), 512, 0, stream>>>(U, psi, bf1, P1, Apack);
    k_prep2<<<(NN * 96) / 256, 256, 0, stream>>>(P1, bf2);
    k_passP<6, 6><<<dim3(NN / 16, 4, 1), 512, 0, stream>>>(Apack, bf2, P2);
    k_prep3<<<(NN * 288) / 256, 256, 0, stream>>>(P2, bf3);
    k_passP<6, 18><<<dim3(NN / 16, 1, 3), 512, 0, stream>>>(Apack, bf3, P3);

    // GAT stage
    k_hes<<<(GG * NN * 64) / 256, 256, 0, stream>>>(P1, P2, P3, gatW, attS, attD, h, es, ed);
    k_gat<<<(GG * NN * 64) / 256, 256, 0, stream>>>(h, es, ed, offs, cnt, csr, gatb, gact);
    k_mlp<<<(GG * NN * 64) / 256, 256, 0, stream>>>(gact, mlpW, mlpb, feat);
    k_final<<<(NN * 64) / 256, 256, 0, stream>>>(feat, oW, ob, out);
}